// Round 20
// baseline (30.403 us; speedup 1.0000x reference)
//
#include <hip/hip_runtime.h>

#define NB 8
#define NT 1024
#define NK 8
#define NL 1024
#define NH 256
#define NE 128
#define NF 64
#define NV 23

typedef __attribute__((ext_vector_type(8))) short bf16x8;
typedef __attribute__((ext_vector_type(4))) float f32x4;

// cvt_pk asm: ONLY for memory-loaded values. NEVER feed MFMA accumulator
// outputs to this (AGPR-resident operands + raw "v" asm => NaN; R11/R19).
__device__ __forceinline__ unsigned cvt_pk_bf16(float lo, float hi) {
  unsigned r;
  asm("v_cvt_pk_bf16_f32 %0, %1, %2" : "=v"(r) : "v"(lo), "v"(hi));
  return r;
}

__device__ __forceinline__ uint4 pack8(const float4 f0, const float4 f1) {
  uint4 u;
  u.x = cvt_pk_bf16(f0.x, f0.y);
  u.y = cvt_pk_bf16(f0.z, f0.w);
  u.z = cvt_pk_bf16(f1.x, f1.y);
  u.w = cvt_pk_bf16(f1.z, f1.w);
  return u;
}

// Accumulator-safe bf16 pack (plain ops; compiler handles AGPR reads).
__device__ __forceinline__ unsigned short f2bf(float f) {
  unsigned u = __float_as_uint(f);
  u += 0x7fffu + ((u >> 16) & 1u);
  return (unsigned short)(u >> 16);
}
__device__ __forceinline__ unsigned pack2bf(float lo, float hi) {
  return (unsigned)f2bf(lo) | ((unsigned)f2bf(hi) << 16);
}

__device__ __forceinline__ float bf_lo(unsigned u) {
  return __uint_as_float(u << 16);
}
__device__ __forceinline__ float bf_hi(unsigned u) {
  return __uint_as_float(u & 0xffff0000u);
}

// ---------------------------------------------------------------------------
// Prep: two pre-swizzled bf16 images of W1 slices (chunk = 8 k x 1 n, 16 B).
//  imgEx (4096 chunks): g in [0,16)  -> W1 rows 256+g*8..+7   (ex slice)
//  imgB (10240 chunks): g in [0,32)  -> W1 rows g*8..+7       (hs slice)
//                       g in [32,40) -> W1 rows 384+(g-32)*8  (col slice)
//  chunk address: g*256 + (n ^ (g&7)).  56 blocks x 64 thr: low latency.
// ---------------------------------------------------------------------------
__global__ __launch_bounds__(64) void k_prep(const float* __restrict__ W1,
                                             uint4* __restrict__ imgEx,
                                             uint4* __restrict__ imgB) {
  const int c = blockIdx.x * 64 + threadIdx.x;  // 3584 slots of 4 chunks
  int g, n0, wrow0;
  uint4* img;
  if (c < 1024) {
    g = c >> 6; n0 = (c & 63) * 4;
    wrow0 = NH + g * 8;
    img = imgEx;
  } else {
    const int c2 = c - 1024;
    g = c2 >> 6; n0 = (c2 & 63) * 4;
    wrow0 = (g < 32) ? g * 8 : 384 + (g - 32) * 8;
    img = imgB;
  }
  float4 r[8];
#pragma unroll
  for (int j = 0; j < 8; ++j)
    r[j] = *(const float4*)&W1[(size_t)(wrow0 + j) * NH + n0];
  const float* rf = (const float*)r;
#pragma unroll
  for (int d = 0; d < 4; ++d) {
    uint4 u;
    u.x = cvt_pk_bf16(rf[0 * 4 + d], rf[1 * 4 + d]);
    u.y = cvt_pk_bf16(rf[2 * 4 + d], rf[3 * 4 + d]);
    u.z = cvt_pk_bf16(rf[4 * 4 + d], rf[5 * 4 + d]);
    u.w = cvt_pk_bf16(rf[6 * 4 + d], rf[7 * 4 + d]);
    img[g * 256 + ((n0 + d) ^ (g & 7))] = u;
  }
}

// ---------------------------------------------------------------------------
// Mega kernel: R18 structure (N-split economy + global-B + 2 blocks/CU)
// with (1) bf16 Ub via accumulator-safe f2bf (halved Ub LDS traffic, 51 KB)
// and (2) base imgB B-loads for ks 0..2 hoisted above the pack/ds_write
// block so they ride out the barrier-1 drain in flight.
// Block = (b, 16 t rows) = 128 ex rows, 8 waves (512 thr), VGPR<=128.
// Wave = (wm = w&3: 32 rows = 2 A-frags, wn = w>>2: 128-wide N-half).
// ---------------------------------------------------------------------------
__global__ __launch_bounds__(512, 4) void k_mega(
    const float* __restrict__ hs, const float* __restrict__ ex,
    const float* __restrict__ col, const int* __restrict__ c_t,
    const int* __restrict__ aa_ids, const uint4* __restrict__ imgEx,
    const uint4* __restrict__ imgB, const float* __restrict__ b1,
    const float* __restrict__ W2, const float* __restrict__ b2,
    float* __restrict__ p_copy, float* __restrict__ lam) {
  extern __shared__ uint4 smem[];
  uint4* exS = smem;          // 2048 chunks = 32 KB  g*128 + (m ^ (g&7))
  uint4* hsS = smem + 2048;   //  512 chunks =  8 KB  gk*16 + (row ^ (gk&7))
  uint4* colS = smem + 2560;  //  128 chunks =  2 KB  gc*16 + (row ^ (gc&7))
  uint2* UbH = (uint2*)(smem + 2688);    // 1024 uint2 = 8 KB: row*64 + (s^row)
  float* Spart = (float*)(smem + 3200);  // 256 f32 = 1 KB: m*2 + wn

  const int tid = threadIdx.x;
  const int lane = tid & 63;
  const int w = tid >> 6;    // 0..7
  const int lm = lane & 15;
  const int lg = lane >> 4;
  const int bid = blockIdx.x;
  const int b = bid & 7;             // XCD-affine
  const int t0 = (bid >> 3) * 16;

  const int t_local = w * 2 + (lm >> 3);
  const int t = t0 + t_local;
  const int ctv = c_t[b * NT + t];
  const bool valid = ctv >= 0;
  const int c = valid ? ctv : 0;

  // ---- stage issue: hs (row = tid>>5, gk = tid&31) ----
  const int srow = tid >> 5;
  const int sgk = tid & 31;
  const float* hsrc = &hs[((size_t)b * NT + t0 + srow) * NH + sgk * 8];
  const float4 h0 = *(const float4*)hsrc;
  const float4 h1 = *(const float4*)(hsrc + 4);

  // ---- stage issue: col (tid<128: row = tid>>3, gc = tid&7) ----
  float4 cf0, cf1;
  const int crow = tid >> 3;
  const int cgc = tid & 7;
  if (tid < 128) {
    const int cct = c_t[b * NT + t0 + crow];
    const int ccol = cct < 0 ? 0 : cct;
    const float* csrc = &col[((size_t)b * NL + ccol) * NF + cgc * 8];
    cf0 = *(const float4*)csrc;
    cf1 = *(const float4*)(csrc + 4);
  }

  // ---- stage issue: ex gather, coalesced (cc -> m = row, g = k-chunk) ----
  float4 e0[4], e1[4];
  int em[4], eg[4];
#pragma unroll
  for (int i = 0; i < 4; ++i) {
    const int cc = i * 512 + tid;  // 0..2047
    const int m = cc >> 4;         // 0..127 = tt*8 + k
    const int g = cc & 15;
    const int tt = m >> 3;
    const int k = m & 7;
    const int ct2 = c_t[b * NT + t0 + tt];
    const int c2 = ct2 < 0 ? 0 : ct2;
    const float* src = &ex[(((size_t)b * NK + k) * NL + c2) * NE + g * 8];
    e0[i] = *(const float4*)src;
    e1[i] = *(const float4*)(src + 4);
    em[i] = m;
    eg[i] = g;
  }

  // ---- hoisted base B-loads (ks 0..2): in flight across barrier 1 ----
  uint4 bbPre[6];
#pragma unroll
  for (int ks = 0; ks < 3; ++ks) {
    const int gk = ks * 4 + lg;
#pragma unroll
    for (int f = 0; f < 2; ++f) {
      const int n = (w * 2 + f) * 16 + lm;
      bbPre[ks * 2 + f] = imgB[(size_t)gk * 256 + (n ^ (gk & 7))];
    }
  }

  // ---- pack + swizzled ds_write ----
  hsS[sgk * 16 + (srow ^ (sgk & 7))] = pack8(h0, h1);
  if (tid < 128) colS[cgc * 16 + (crow ^ (cgc & 7))] = pack8(cf0, cf1);
#pragma unroll
  for (int i = 0; i < 4; ++i)
    exS[eg[i] * 128 + (em[i] ^ (eg[i] & 7))] = pack8(e0[i], e1[i]);

  __syncthreads();  // barrier 1: staged LDS complete (bbPre still in flight)

  // ---- base: A from LDS, B from bbPre / global imgB ----
  f32x4 accB[2];
#pragma unroll
  for (int f = 0; f < 2; ++f) {
    const float4 bv = *(const float4*)&b1[(w * 2 + f) * 16 + lg * 4];
    accB[f][0] = bv.x; accB[f][1] = bv.y; accB[f][2] = bv.z; accB[f][3] = bv.w;
  }
#pragma unroll
  for (int ks = 0; ks < 10; ++ks) {
    const int gk = ks * 4 + lg;  // 0..39
    union { uint4 u; bf16x8 v; } A;
    A.u = (gk < 32) ? hsS[gk * 16 + (lm ^ (gk & 7))]
                    : colS[(gk - 32) * 16 + (lm ^ ((gk - 32) & 7))];
#pragma unroll
    for (int f = 0; f < 2; ++f) {
      union { uint4 u; bf16x8 v; } B2;
      if (ks < 3) {
        B2.u = bbPre[ks * 2 + f];
      } else {
        const int n = (w * 2 + f) * 16 + lm;
        B2.u = imgB[(size_t)gk * 256 + (n ^ (gk & 7))];
      }
      accB[f] = __builtin_amdgcn_mfma_f32_16x16x32_bf16(B2.v, A.v, accB[f], 0, 0, 0);
    }
  }
#pragma unroll
  for (int f = 0; f < 2; ++f) {
    uint2 o;
    o.x = pack2bf(accB[f][0], accB[f][1]);   // accumulator-safe pack
    o.y = pack2bf(accB[f][2], accB[f][3]);
    UbH[lm * 64 + (((w * 2 + f) * 4 + lg) ^ lm)] = o;
  }

  // ---- phase-4 A-frags: 2 row-frags for wave group wm ----
  const int wm = w & 3;
  const int wn = w >> 2;
  uint4 aPk[2][4];
#pragma unroll
  for (int ks = 0; ks < 4; ++ks) {
    const int g = ks * 4 + lg;
#pragma unroll
    for (int rf = 0; rf < 2; ++rf)
      aPk[rf][ks] = exS[g * 128 + ((wm * 32 + rf * 16 + lm) ^ (g & 7))];
  }

  __syncthreads();  // barrier 2: UbH visible

  // ---- phase 4: wn half only; B from global imgEx; B feeds 2 MFMAs ----
  const float b2v = b2[0];
  f32x4 acc[2][8] = {};
#pragma unroll
  for (int ks = 0; ks < 4; ++ks) {
    const int g = ks * 4 + lg;
    union { uint4 u; bf16x8 v; } A0, A1;
    A0.u = aPk[0][ks];
    A1.u = aPk[1][ks];
#pragma unroll
    for (int fn = 0; fn < 8; ++fn) {
      const int n = wn * 128 + fn * 16 + lm;
      union { uint4 u; bf16x8 v; } B2;
      B2.u = imgEx[(size_t)g * 256 + (n ^ (g & 7))];
      acc[0][fn] = __builtin_amdgcn_mfma_f32_16x16x32_bf16(B2.v, A0.v, acc[0][fn], 0, 0, 0);
      acc[1][fn] = __builtin_amdgcn_mfma_f32_16x16x32_bf16(B2.v, A1.v, acc[1][fn], 0, 0, 0);
    }
  }

  float p[2] = {0.f, 0.f};
#pragma unroll
  for (int fn = 0; fn < 8; ++fn) {
    const int n0 = wn * 128 + fn * 16 + lg * 4;
    const int s = wn * 32 + fn * 4 + lg;
    const float4 w2v = *(const float4*)&W2[n0];
#pragma unroll
    for (int rf = 0; rf < 2; ++rf) {
      const int tl = wm * 4 + rf * 2 + (lm >> 3);
      const uint2 ub = UbH[tl * 64 + (s ^ tl)];
      p[rf] += fmaxf(acc[rf][fn][0] + bf_lo(ub.x), 0.f) * w2v.x +
               fmaxf(acc[rf][fn][1] + bf_hi(ub.x), 0.f) * w2v.y +
               fmaxf(acc[rf][fn][2] + bf_lo(ub.y), 0.f) * w2v.z +
               fmaxf(acc[rf][fn][3] + bf_hi(ub.y), 0.f) * w2v.w;
    }
  }
#pragma unroll
  for (int rf = 0; rf < 2; ++rf) {
    p[rf] += __shfl_xor(p[rf], 16);
    p[rf] += __shfl_xor(p[rf], 32);
  }
  if (lg == 0) {
    Spart[(wm * 32 + lm) * 2 + wn] = p[0];
    Spart[(wm * 32 + 16 + lm) * 2 + wn] = p[1];
  }

  __syncthreads();  // barrier 3: Spart visible

  // ---- final: rows m = w*16 + lm, R13 epilogue verbatim ----
  const float2 sp = *(const float2*)&Spart[(w * 16 + lm) * 2];
  const float score = sp.x + sp.y + b2v;

  float mx = score;
  mx = fmaxf(mx, __shfl_xor(mx, 1));
  mx = fmaxf(mx, __shfl_xor(mx, 2));
  mx = fmaxf(mx, __shfl_xor(mx, 4));
  const float e = __expf(score - mx);
  float s = e;
  s += __shfl_xor(s, 1);
  s += __shfl_xor(s, 2);
  s += __shfl_xor(s, 4);
  const float wgt = valid ? (e / s) : 0.f;

  if (lg == 0) lam[((size_t)b * NT + t0 + w * 2) * NK + lm] = wgt;

  int aav = 0;
  if (lg == 0) aav = aa_ids[((size_t)b * NK + (lm & 7)) * NL + c];

  const int bin = lane & 31;
  const int half = lane >> 5;
  const int src0 = half * 8;
  float pc = 0.f;
#pragma unroll
  for (int k = 0; k < 8; ++k) {
    const int a = __shfl(aav, src0 + k);
    const float ww = __shfl(wgt, src0 + k);
    pc += (a == bin) ? ww : 0.f;
  }
  if (bin < NV)
    p_copy[((size_t)b * NT + t0 + w * 2 + half) * NV + bin] = pc;
}

extern "C" void kernel_launch(void* const* d_in, const int* in_sizes, int n_in,
                              void* d_out, int out_size, void* d_ws, size_t ws_size,
                              hipStream_t stream) {
  const float* hs = (const float*)d_in[0];
  const float* ex = (const float*)d_in[1];
  const float* col = (const float*)d_in[2];
  const int* ct = (const int*)d_in[3];
  const int* aa = (const int*)d_in[4];
  const float* W1 = (const float*)d_in[5];
  const float* b1 = (const float*)d_in[6];
  const float* W2 = (const float*)d_in[7];
  const float* b2 = (const float*)d_in[8];

  uint4* imgEx = (uint4*)d_ws;        // 64 KB
  uint4* imgB = imgEx + 4096;         // 160 KB

  float* p_copy = (float*)d_out;
  float* lam = p_copy + (size_t)NB * NT * NV;

  const size_t lds_bytes = 3264 * sizeof(uint4);  // 51 KB -> 2 blocks/CU

  k_prep<<<56, 64, 0, stream>>>(W1, imgEx, imgB);
  k_mega<<<512, 512, lds_bytes, stream>>>(hs, ex, col, ct, aa, imgEx, imgB,
                                          b1, W2, b2, p_copy, lam);
}

// Round 21
// 27.893 us; speedup vs baseline: 1.0900x; 1.0900x over previous
//
#include <hip/hip_runtime.h>

#define NB 8
#define NT 1024
#define NK 8
#define NL 1024
#define NH 256
#define NE 128
#define NF 64
#define NV 23

typedef __attribute__((ext_vector_type(8))) short bf16x8;
typedef __attribute__((ext_vector_type(4))) float f32x4;

// cvt_pk asm: ONLY for memory-loaded values. NEVER feed MFMA accumulator
// outputs to this (AGPR-resident operands + raw "v" asm => NaN; R11/R19).
__device__ __forceinline__ unsigned cvt_pk_bf16(float lo, float hi) {
  unsigned r;
  asm("v_cvt_pk_bf16_f32 %0, %1, %2" : "=v"(r) : "v"(lo), "v"(hi));
  return r;
}

__device__ __forceinline__ uint4 pack8(const float4 f0, const float4 f1) {
  uint4 u;
  u.x = cvt_pk_bf16(f0.x, f0.y);
  u.y = cvt_pk_bf16(f0.z, f0.w);
  u.z = cvt_pk_bf16(f1.x, f1.y);
  u.w = cvt_pk_bf16(f1.z, f1.w);
  return u;
}

// ---------------------------------------------------------------------------
// Prep: two pre-swizzled bf16 images of W1 slices (chunk = 8 k x 1 n, 16 B).
//  imgEx (4096 chunks): g in [0,16)  -> W1 rows 256+g*8..+7   (ex slice)
//  imgB (10240 chunks): g in [0,32)  -> W1 rows g*8..+7       (hs slice)
//                       g in [32,40) -> W1 rows 384+(g-32)*8  (col slice)
//  chunk address: g*256 + (n ^ (g&7)).  56 blocks x 64 thr: low latency.
// ---------------------------------------------------------------------------
__global__ __launch_bounds__(64) void k_prep(const float* __restrict__ W1,
                                             uint4* __restrict__ imgEx,
                                             uint4* __restrict__ imgB) {
  const int c = blockIdx.x * 64 + threadIdx.x;  // 3584 slots of 4 chunks
  int g, n0, wrow0;
  uint4* img;
  if (c < 1024) {
    g = c >> 6; n0 = (c & 63) * 4;
    wrow0 = NH + g * 8;
    img = imgEx;
  } else {
    const int c2 = c - 1024;
    g = c2 >> 6; n0 = (c2 & 63) * 4;
    wrow0 = (g < 32) ? g * 8 : 384 + (g - 32) * 8;
    img = imgB;
  }
  float4 r[8];
#pragma unroll
  for (int j = 0; j < 8; ++j)
    r[j] = *(const float4*)&W1[(size_t)(wrow0 + j) * NH + n0];
  const float* rf = (const float*)r;
#pragma unroll
  for (int d = 0; d < 4; ++d) {
    uint4 u;
    u.x = cvt_pk_bf16(rf[0 * 4 + d], rf[1 * 4 + d]);
    u.y = cvt_pk_bf16(rf[2 * 4 + d], rf[3 * 4 + d]);
    u.z = cvt_pk_bf16(rf[4 * 4 + d], rf[5 * 4 + d]);
    u.w = cvt_pk_bf16(rf[6 * 4 + d], rf[7 * 4 + d]);
    img[g * 256 + ((n0 + d) ^ (g & 7))] = u;
  }
}

// ---------------------------------------------------------------------------
// Mega kernel: R18 structure verbatim (N-split economy + global-B +
// 2 blocks/CU) + s_setprio(1) around the phase-4 MFMA-dense loop (T5:
// favors the MFMA-entering block over the co-resident staging block).
// Block = (b, 16 t rows) = 128 ex rows, 8 waves (512 thr), LDS = 59 KB,
// VGPR <= 128 via (512,4) -> 2 resident blocks/CU (inter-block overlap).
// Wave = (wm = w&3: 32 rows = 2 A-frags, wn = w>>2: 128-wide N-half).
// ---------------------------------------------------------------------------
__global__ __launch_bounds__(512, 4) void k_mega(
    const float* __restrict__ hs, const float* __restrict__ ex,
    const float* __restrict__ col, const int* __restrict__ c_t,
    const int* __restrict__ aa_ids, const uint4* __restrict__ imgEx,
    const uint4* __restrict__ imgB, const float* __restrict__ b1,
    const float* __restrict__ W2, const float* __restrict__ b2,
    float* __restrict__ p_copy, float* __restrict__ lam) {
  extern __shared__ uint4 smem[];
  uint4* exS = smem;          // 2048 chunks = 32 KB  g*128 + (m ^ (g&7))
  uint4* hsS = smem + 2048;   //  512 chunks =  8 KB  gk*16 + (row ^ (gk&7))
  uint4* colS = smem + 2560;  //  128 chunks =  2 KB  gc*16 + (row ^ (gc&7))
  uint4* Ub = smem + 2688;    // 1024 chunks = 16 KB  row*64 + (slot ^ row)
  float* Spart = (float*)(smem + 3712);  // 256 f32 = 1 KB: m*2 + wn

  const int tid = threadIdx.x;
  const int lane = tid & 63;
  const int w = tid >> 6;    // 0..7
  const int lm = lane & 15;
  const int lg = lane >> 4;
  const int bid = blockIdx.x;
  const int b = bid & 7;             // XCD-affine
  const int t0 = (bid >> 3) * 16;

  const int t_local = w * 2 + (lm >> 3);
  const int t = t0 + t_local;
  const int ctv = c_t[b * NT + t];
  const bool valid = ctv >= 0;
  const int c = valid ? ctv : 0;

  // ---- stage issue: hs (row = tid>>5, gk = tid&31) ----
  const int srow = tid >> 5;
  const int sgk = tid & 31;
  const float* hsrc = &hs[((size_t)b * NT + t0 + srow) * NH + sgk * 8];
  const float4 h0 = *(const float4*)hsrc;
  const float4 h1 = *(const float4*)(hsrc + 4);

  // ---- stage issue: col (tid<128: row = tid>>3, gc = tid&7) ----
  float4 cf0, cf1;
  const int crow = tid >> 3;
  const int cgc = tid & 7;
  if (tid < 128) {
    const int cct = c_t[b * NT + t0 + crow];
    const int ccol = cct < 0 ? 0 : cct;
    const float* csrc = &col[((size_t)b * NL + ccol) * NF + cgc * 8];
    cf0 = *(const float4*)csrc;
    cf1 = *(const float4*)(csrc + 4);
  }

  // ---- stage issue: ex gather, coalesced (cc -> m = row, g = k-chunk) ----
  float4 e0[4], e1[4];
  int em[4], eg[4];
#pragma unroll
  for (int i = 0; i < 4; ++i) {
    const int cc = i * 512 + tid;  // 0..2047
    const int m = cc >> 4;         // 0..127 = tt*8 + k
    const int g = cc & 15;
    const int tt = m >> 3;
    const int k = m & 7;
    const int ct2 = c_t[b * NT + t0 + tt];
    const int c2 = ct2 < 0 ? 0 : ct2;
    const float* src = &ex[(((size_t)b * NK + k) * NL + c2) * NE + g * 8];
    e0[i] = *(const float4*)src;
    e1[i] = *(const float4*)(src + 4);
    em[i] = m;
    eg[i] = g;
  }

  // ---- pack + swizzled ds_write ----
  hsS[sgk * 16 + (srow ^ (sgk & 7))] = pack8(h0, h1);
  if (tid < 128) colS[cgc * 16 + (crow ^ (cgc & 7))] = pack8(cf0, cf1);
#pragma unroll
  for (int i = 0; i < 4; ++i)
    exS[eg[i] * 128 + (em[i] ^ (eg[i] & 7))] = pack8(e0[i], e1[i]);

  __syncthreads();  // barrier 1: staged LDS complete

  // ---- base: A from LDS, B from global imgB ----
  f32x4 accB[2];
#pragma unroll
  for (int f = 0; f < 2; ++f) {
    const float4 bv = *(const float4*)&b1[(w * 2 + f) * 16 + lg * 4];
    accB[f][0] = bv.x; accB[f][1] = bv.y; accB[f][2] = bv.z; accB[f][3] = bv.w;
  }
#pragma unroll
  for (int ks = 0; ks < 10; ++ks) {
    const int gk = ks * 4 + lg;  // 0..39
    union { uint4 u; bf16x8 v; } A;
    A.u = (gk < 32) ? hsS[gk * 16 + (lm ^ (gk & 7))]
                    : colS[(gk - 32) * 16 + (lm ^ ((gk - 32) & 7))];
#pragma unroll
    for (int f = 0; f < 2; ++f) {
      const int n = (w * 2 + f) * 16 + lm;
      union { uint4 u; bf16x8 v; } B2;
      B2.u = imgB[(size_t)gk * 256 + (n ^ (gk & 7))];
      accB[f] = __builtin_amdgcn_mfma_f32_16x16x32_bf16(B2.v, A.v, accB[f], 0, 0, 0);
    }
  }
#pragma unroll
  for (int f = 0; f < 2; ++f) {
    union { uint4 u; f32x4 v; } o;
    o.v = accB[f];
    Ub[lm * 64 + (((w * 2 + f) * 4 + lg) ^ lm)] = o.u;
  }

  // ---- phase-4 A-frags: 2 row-frags for wave group wm ----
  const int wm = w & 3;
  const int wn = w >> 2;
  uint4 aPk[2][4];
#pragma unroll
  for (int ks = 0; ks < 4; ++ks) {
    const int g = ks * 4 + lg;
#pragma unroll
    for (int rf = 0; rf < 2; ++rf)
      aPk[rf][ks] = exS[g * 128 + ((wm * 32 + rf * 16 + lm) ^ (g & 7))];
  }

  __syncthreads();  // barrier 2: Ub visible

  // ---- phase 4: wn half only; B from global imgEx; B feeds 2 MFMAs ----
  const float b2v = b2[0];
  f32x4 acc[2][8] = {};
  __builtin_amdgcn_s_setprio(1);  // T5: favor MFMA-dense phase vs staging block
#pragma unroll
  for (int ks = 0; ks < 4; ++ks) {
    const int g = ks * 4 + lg;
    union { uint4 u; bf16x8 v; } A0, A1;
    A0.u = aPk[0][ks];
    A1.u = aPk[1][ks];
#pragma unroll
    for (int fn = 0; fn < 8; ++fn) {
      const int n = wn * 128 + fn * 16 + lm;
      union { uint4 u; bf16x8 v; } B2;
      B2.u = imgEx[(size_t)g * 256 + (n ^ (g & 7))];
      acc[0][fn] = __builtin_amdgcn_mfma_f32_16x16x32_bf16(B2.v, A0.v, acc[0][fn], 0, 0, 0);
      acc[1][fn] = __builtin_amdgcn_mfma_f32_16x16x32_bf16(B2.v, A1.v, acc[1][fn], 0, 0, 0);
    }
  }
  __builtin_amdgcn_s_setprio(0);

  float p[2] = {0.f, 0.f};
#pragma unroll
  for (int fn = 0; fn < 8; ++fn) {
    const int n0 = wn * 128 + fn * 16 + lg * 4;
    const int s = wn * 32 + fn * 4 + lg;
    const float4 w2v = *(const float4*)&W2[n0];
#pragma unroll
    for (int rf = 0; rf < 2; ++rf) {
      const int tl = wm * 4 + rf * 2 + (lm >> 3);
      union { uint4 u; f32x4 v; } ubv;
      ubv.u = Ub[tl * 64 + (s ^ tl)];
      p[rf] += fmaxf(acc[rf][fn][0] + ubv.v[0], 0.f) * w2v.x +
               fmaxf(acc[rf][fn][1] + ubv.v[1], 0.f) * w2v.y +
               fmaxf(acc[rf][fn][2] + ubv.v[2], 0.f) * w2v.z +
               fmaxf(acc[rf][fn][3] + ubv.v[3], 0.f) * w2v.w;
    }
  }
#pragma unroll
  for (int rf = 0; rf < 2; ++rf) {
    p[rf] += __shfl_xor(p[rf], 16);
    p[rf] += __shfl_xor(p[rf], 32);
  }
  if (lg == 0) {
    Spart[(wm * 32 + lm) * 2 + wn] = p[0];
    Spart[(wm * 32 + 16 + lm) * 2 + wn] = p[1];
  }

  __syncthreads();  // barrier 3: Spart visible

  // ---- final: rows m = w*16 + lm, R13 epilogue verbatim ----
  const float2 sp = *(const float2*)&Spart[(w * 16 + lm) * 2];
  const float score = sp.x + sp.y + b2v;

  float mx = score;
  mx = fmaxf(mx, __shfl_xor(mx, 1));
  mx = fmaxf(mx, __shfl_xor(mx, 2));
  mx = fmaxf(mx, __shfl_xor(mx, 4));
  const float e = __expf(score - mx);
  float s = e;
  s += __shfl_xor(s, 1);
  s += __shfl_xor(s, 2);
  s += __shfl_xor(s, 4);
  const float wgt = valid ? (e / s) : 0.f;

  if (lg == 0) lam[((size_t)b * NT + t0 + w * 2) * NK + lm] = wgt;

  int aav = 0;
  if (lg == 0) aav = aa_ids[((size_t)b * NK + (lm & 7)) * NL + c];

  const int bin = lane & 31;
  const int half = lane >> 5;
  const int src0 = half * 8;
  float pc = 0.f;
#pragma unroll
  for (int k = 0; k < 8; ++k) {
    const int a = __shfl(aav, src0 + k);
    const float ww = __shfl(wgt, src0 + k);
    pc += (a == bin) ? ww : 0.f;
  }
  if (bin < NV)
    p_copy[((size_t)b * NT + t0 + w * 2 + half) * NV + bin] = pc;
}

extern "C" void kernel_launch(void* const* d_in, const int* in_sizes, int n_in,
                              void* d_out, int out_size, void* d_ws, size_t ws_size,
                              hipStream_t stream) {
  const float* hs = (const float*)d_in[0];
  const float* ex = (const float*)d_in[1];
  const float* col = (const float*)d_in[2];
  const int* ct = (const int*)d_in[3];
  const int* aa = (const int*)d_in[4];
  const float* W1 = (const float*)d_in[5];
  const float* b1 = (const float*)d_in[6];
  const float* W2 = (const float*)d_in[7];
  const float* b2 = (const float*)d_in[8];

  uint4* imgEx = (uint4*)d_ws;        // 64 KB
  uint4* imgB = imgEx + 4096;         // 160 KB

  float* p_copy = (float*)d_out;
  float* lam = p_copy + (size_t)NB * NT * NV;

  const size_t lds_bytes = 3712 * sizeof(uint4) + 256 * sizeof(float);  // 59 KB

  k_prep<<<56, 64, 0, stream>>>(W1, imgEx, imgB);
  k_mega<<<512, 512, lds_bytes, stream>>>(hs, ex, col, ct, aa, imgEx, imgB,
                                          b1, W2, b2, p_copy, lam);
}

// Round 22
// 23.788 us; speedup vs baseline: 1.2780x; 1.1726x over previous
//
#include <hip/hip_runtime.h>

#define NB 8
#define NT 1024
#define NK 8
#define NL 1024
#define NH 256
#define NE 128
#define NF 64
#define NV 23

typedef __attribute__((ext_vector_type(8))) short bf16x8;
typedef __attribute__((ext_vector_type(4))) float f32x4;

// cvt_pk asm: ONLY for memory-loaded values. NEVER feed MFMA accumulator
// outputs to this (AGPR-resident operands + raw "v" asm => NaN; R11/R19).
__device__ __forceinline__ unsigned cvt_pk_bf16(float lo, float hi) {
  unsigned r;
  asm("v_cvt_pk_bf16_f32 %0, %1, %2" : "=v"(r) : "v"(lo), "v"(hi));
  return r;
}

__device__ __forceinline__ uint4 pack8(const float4 f0, const float4 f1) {
  uint4 u;
  u.x = cvt_pk_bf16(f0.x, f0.y);
  u.y = cvt_pk_bf16(f0.z, f0.w);
  u.z = cvt_pk_bf16(f1.x, f1.y);
  u.w = cvt_pk_bf16(f1.z, f1.w);
  return u;
}

// ---------------------------------------------------------------------------
// Prep: two pre-swizzled bf16 images of W1 slices (chunk = 8 k x 1 n, 16 B).
//  imgEx (4096 chunks): g in [0,16)  -> W1 rows 256+g*8..+7   (ex slice)
//  imgB (10240 chunks): g in [0,32)  -> W1 rows g*8..+7       (hs slice)
//                       g in [32,40) -> W1 rows 384+(g-32)*8  (col slice)
//  chunk address: g*256 + (n ^ (g&7)).  56 blocks x 64 thr: low latency.
// ---------------------------------------------------------------------------
__global__ __launch_bounds__(64) void k_prep(const float* __restrict__ W1,
                                             uint4* __restrict__ imgEx,
                                             uint4* __restrict__ imgB) {
  const int c = blockIdx.x * 64 + threadIdx.x;  // 3584 slots of 4 chunks
  int g, n0, wrow0;
  uint4* img;
  if (c < 1024) {
    g = c >> 6; n0 = (c & 63) * 4;
    wrow0 = NH + g * 8;
    img = imgEx;
  } else {
    const int c2 = c - 1024;
    g = c2 >> 6; n0 = (c2 & 63) * 4;
    wrow0 = (g < 32) ? g * 8 : 384 + (g - 32) * 8;
    img = imgB;
  }
  float4 r[8];
#pragma unroll
  for (int j = 0; j < 8; ++j)
    r[j] = *(const float4*)&W1[(size_t)(wrow0 + j) * NH + n0];
  const float* rf = (const float*)r;
#pragma unroll
  for (int d = 0; d < 4; ++d) {
    uint4 u;
    u.x = cvt_pk_bf16(rf[0 * 4 + d], rf[1 * 4 + d]);
    u.y = cvt_pk_bf16(rf[2 * 4 + d], rf[3 * 4 + d]);
    u.z = cvt_pk_bf16(rf[4 * 4 + d], rf[5 * 4 + d]);
    u.w = cvt_pk_bf16(rf[6 * 4 + d], rf[7 * 4 + d]);
    img[g * 256 + ((n0 + d) ^ (g & 7))] = u;
  }
}

// ---------------------------------------------------------------------------
// Mega kernel: R18 structure verbatim (N-split economy + global-B +
// 2 blocks/CU). NO setprio: R21 showed biasing MFMA waves starves the
// co-resident block's staging and breaks the inter-block overlap.
// Block = (b, 16 t rows) = 128 ex rows, 8 waves (512 thr), LDS = 59 KB,
// VGPR <= 128 via (512,4) -> 2 resident blocks/CU (inter-block overlap).
// Wave = (wm = w&3: 32 rows = 2 A-frags, wn = w>>2: 128-wide N-half):
// each B-frag read feeds 2 MFMAs; B-frags from GLOBAL imgEx/imgB (L1/L2-hot).
// ---------------------------------------------------------------------------
__global__ __launch_bounds__(512, 4) void k_mega(
    const float* __restrict__ hs, const float* __restrict__ ex,
    const float* __restrict__ col, const int* __restrict__ c_t,
    const int* __restrict__ aa_ids, const uint4* __restrict__ imgEx,
    const uint4* __restrict__ imgB, const float* __restrict__ b1,
    const float* __restrict__ W2, const float* __restrict__ b2,
    float* __restrict__ p_copy, float* __restrict__ lam) {
  extern __shared__ uint4 smem[];
  uint4* exS = smem;          // 2048 chunks = 32 KB  g*128 + (m ^ (g&7))
  uint4* hsS = smem + 2048;   //  512 chunks =  8 KB  gk*16 + (row ^ (gk&7))
  uint4* colS = smem + 2560;  //  128 chunks =  2 KB  gc*16 + (row ^ (gc&7))
  uint4* Ub = smem + 2688;    // 1024 chunks = 16 KB  row*64 + (slot ^ row)
  float* Spart = (float*)(smem + 3712);  // 256 f32 = 1 KB: m*2 + wn

  const int tid = threadIdx.x;
  const int lane = tid & 63;
  const int w = tid >> 6;    // 0..7
  const int lm = lane & 15;
  const int lg = lane >> 4;
  const int bid = blockIdx.x;
  const int b = bid & 7;             // XCD-affine
  const int t0 = (bid >> 3) * 16;

  const int t_local = w * 2 + (lm >> 3);
  const int t = t0 + t_local;
  const int ctv = c_t[b * NT + t];
  const bool valid = ctv >= 0;
  const int c = valid ? ctv : 0;

  // ---- stage issue: hs (row = tid>>5, gk = tid&31) ----
  const int srow = tid >> 5;
  const int sgk = tid & 31;
  const float* hsrc = &hs[((size_t)b * NT + t0 + srow) * NH + sgk * 8];
  const float4 h0 = *(const float4*)hsrc;
  const float4 h1 = *(const float4*)(hsrc + 4);

  // ---- stage issue: col (tid<128: row = tid>>3, gc = tid&7) ----
  float4 cf0, cf1;
  const int crow = tid >> 3;
  const int cgc = tid & 7;
  if (tid < 128) {
    const int cct = c_t[b * NT + t0 + crow];
    const int ccol = cct < 0 ? 0 : cct;
    const float* csrc = &col[((size_t)b * NL + ccol) * NF + cgc * 8];
    cf0 = *(const float4*)csrc;
    cf1 = *(const float4*)(csrc + 4);
  }

  // ---- stage issue: ex gather, coalesced (cc -> m = row, g = k-chunk) ----
  float4 e0[4], e1[4];
  int em[4], eg[4];
#pragma unroll
  for (int i = 0; i < 4; ++i) {
    const int cc = i * 512 + tid;  // 0..2047
    const int m = cc >> 4;         // 0..127 = tt*8 + k
    const int g = cc & 15;
    const int tt = m >> 3;
    const int k = m & 7;
    const int ct2 = c_t[b * NT + t0 + tt];
    const int c2 = ct2 < 0 ? 0 : ct2;
    const float* src = &ex[(((size_t)b * NK + k) * NL + c2) * NE + g * 8];
    e0[i] = *(const float4*)src;
    e1[i] = *(const float4*)(src + 4);
    em[i] = m;
    eg[i] = g;
  }

  // ---- pack + swizzled ds_write ----
  hsS[sgk * 16 + (srow ^ (sgk & 7))] = pack8(h0, h1);
  if (tid < 128) colS[cgc * 16 + (crow ^ (cgc & 7))] = pack8(cf0, cf1);
#pragma unroll
  for (int i = 0; i < 4; ++i)
    exS[eg[i] * 128 + (em[i] ^ (eg[i] & 7))] = pack8(e0[i], e1[i]);

  __syncthreads();  // barrier 1: staged LDS complete

  // ---- base: A from LDS, B from global imgB ----
  f32x4 accB[2];
#pragma unroll
  for (int f = 0; f < 2; ++f) {
    const float4 bv = *(const float4*)&b1[(w * 2 + f) * 16 + lg * 4];
    accB[f][0] = bv.x; accB[f][1] = bv.y; accB[f][2] = bv.z; accB[f][3] = bv.w;
  }
#pragma unroll
  for (int ks = 0; ks < 10; ++ks) {
    const int gk = ks * 4 + lg;  // 0..39
    union { uint4 u; bf16x8 v; } A;
    A.u = (gk < 32) ? hsS[gk * 16 + (lm ^ (gk & 7))]
                    : colS[(gk - 32) * 16 + (lm ^ ((gk - 32) & 7))];
#pragma unroll
    for (int f = 0; f < 2; ++f) {
      const int n = (w * 2 + f) * 16 + lm;
      union { uint4 u; bf16x8 v; } B2;
      B2.u = imgB[(size_t)gk * 256 + (n ^ (gk & 7))];
      accB[f] = __builtin_amdgcn_mfma_f32_16x16x32_bf16(B2.v, A.v, accB[f], 0, 0, 0);
    }
  }
#pragma unroll
  for (int f = 0; f < 2; ++f) {
    union { uint4 u; f32x4 v; } o;
    o.v = accB[f];
    Ub[lm * 64 + (((w * 2 + f) * 4 + lg) ^ lm)] = o.u;
  }

  // ---- phase-4 A-frags: 2 row-frags for wave group wm ----
  const int wm = w & 3;
  const int wn = w >> 2;
  uint4 aPk[2][4];
#pragma unroll
  for (int ks = 0; ks < 4; ++ks) {
    const int g = ks * 4 + lg;
#pragma unroll
    for (int rf = 0; rf < 2; ++rf)
      aPk[rf][ks] = exS[g * 128 + ((wm * 32 + rf * 16 + lm) ^ (g & 7))];
  }

  __syncthreads();  // barrier 2: Ub visible

  // ---- phase 4: wn half only; B from global imgEx; B feeds 2 MFMAs ----
  const float b2v = b2[0];
  f32x4 acc[2][8] = {};
#pragma unroll
  for (int ks = 0; ks < 4; ++ks) {
    const int g = ks * 4 + lg;
    union { uint4 u; bf16x8 v; } A0, A1;
    A0.u = aPk[0][ks];
    A1.u = aPk[1][ks];
#pragma unroll
    for (int fn = 0; fn < 8; ++fn) {
      const int n = wn * 128 + fn * 16 + lm;
      union { uint4 u; bf16x8 v; } B2;
      B2.u = imgEx[(size_t)g * 256 + (n ^ (g & 7))];
      acc[0][fn] = __builtin_amdgcn_mfma_f32_16x16x32_bf16(B2.v, A0.v, acc[0][fn], 0, 0, 0);
      acc[1][fn] = __builtin_amdgcn_mfma_f32_16x16x32_bf16(B2.v, A1.v, acc[1][fn], 0, 0, 0);
    }
  }

  float p[2] = {0.f, 0.f};
#pragma unroll
  for (int fn = 0; fn < 8; ++fn) {
    const int n0 = wn * 128 + fn * 16 + lg * 4;
    const int s = wn * 32 + fn * 4 + lg;
    const float4 w2v = *(const float4*)&W2[n0];
#pragma unroll
    for (int rf = 0; rf < 2; ++rf) {
      const int tl = wm * 4 + rf * 2 + (lm >> 3);
      union { uint4 u; f32x4 v; } ubv;
      ubv.u = Ub[tl * 64 + (s ^ tl)];
      p[rf] += fmaxf(acc[rf][fn][0] + ubv.v[0], 0.f) * w2v.x +
               fmaxf(acc[rf][fn][1] + ubv.v[1], 0.f) * w2v.y +
               fmaxf(acc[rf][fn][2] + ubv.v[2], 0.f) * w2v.z +
               fmaxf(acc[rf][fn][3] + ubv.v[3], 0.f) * w2v.w;
    }
  }
#pragma unroll
  for (int rf = 0; rf < 2; ++rf) {
    p[rf] += __shfl_xor(p[rf], 16);
    p[rf] += __shfl_xor(p[rf], 32);
  }
  if (lg == 0) {
    Spart[(wm * 32 + lm) * 2 + wn] = p[0];
    Spart[(wm * 32 + 16 + lm) * 2 + wn] = p[1];
  }

  __syncthreads();  // barrier 3: Spart visible

  // ---- final: rows m = w*16 + lm, R13 epilogue verbatim ----
  const float2 sp = *(const float2*)&Spart[(w * 16 + lm) * 2];
  const float score = sp.x + sp.y + b2v;

  float mx = score;
  mx = fmaxf(mx, __shfl_xor(mx, 1));
  mx = fmaxf(mx, __shfl_xor(mx, 2));
  mx = fmaxf(mx, __shfl_xor(mx, 4));
  const float e = __expf(score - mx);
  float s = e;
  s += __shfl_xor(s, 1);
  s += __shfl_xor(s, 2);
  s += __shfl_xor(s, 4);
  const float wgt = valid ? (e / s) : 0.f;

  if (lg == 0) lam[((size_t)b * NT + t0 + w * 2) * NK + lm] = wgt;

  int aav = 0;
  if (lg == 0) aav = aa_ids[((size_t)b * NK + (lm & 7)) * NL + c];

  const int bin = lane & 31;
  const int half = lane >> 5;
  const int src0 = half * 8;
  float pc = 0.f;
#pragma unroll
  for (int k = 0; k < 8; ++k) {
    const int a = __shfl(aav, src0 + k);
    const float ww = __shfl(wgt, src0 + k);
    pc += (a == bin) ? ww : 0.f;
  }
  if (bin < NV)
    p_copy[((size_t)b * NT + t0 + w * 2 + half) * NV + bin] = pc;
}

extern "C" void kernel_launch(void* const* d_in, const int* in_sizes, int n_in,
                              void* d_out, int out_size, void* d_ws, size_t ws_size,
                              hipStream_t stream) {
  const float* hs = (const float*)d_in[0];
  const float* ex = (const float*)d_in[1];
  const float* col = (const float*)d_in[2];
  const int* ct = (const int*)d_in[3];
  const int* aa = (const int*)d_in[4];
  const float* W1 = (const float*)d_in[5];
  const float* b1 = (const float*)d_in[6];
  const float* W2 = (const float*)d_in[7];
  const float* b2 = (const float*)d_in[8];

  uint4* imgEx = (uint4*)d_ws;        // 64 KB
  uint4* imgB = imgEx + 4096;         // 160 KB

  float* p_copy = (float*)d_out;
  float* lam = p_copy + (size_t)NB * NT * NV;

  const size_t lds_bytes = 3712 * sizeof(uint4) + 256 * sizeof(float);  // 59 KB

  k_prep<<<56, 64, 0, stream>>>(W1, imgEx, imgB);
  k_mega<<<512, 512, lds_bytes, stream>>>(hs, ex, col, ct, aa, imgEx, imgB,
                                          b1, W2, b2, p_copy, lam);
}